// Round 11
// baseline (77.476 us; speedup 1.0000x reference)
//
#include <hip/hip_runtime.h>
#include <math.h>

#define D_FEAT 128
#define D_DOT  4
#define U      8    // row-groups per wave; 32 rows/wave, 128 rows/block

// Structure (validated R10): one merged pure-stream projection kernel
// (blockIdx-partitioned edges|nodes, no sync needed) + tiny gather epilogue.
// 16 lanes per row aligned to DPP rows; DPP row_ror reduce (pure VALU).
// Row streams non-temporal; q/pn stay normally cached (L2/L3 absorb).

typedef float vfloat4 __attribute__((ext_vector_type(4)));

__device__ __forceinline__ float dot4v(const vfloat4 a, const float4 b) {
    return a.x * b.x + a.y * b.y + a.z * b.z + a.w * b.w;
}

__device__ __forceinline__ vfloat4 ntload4(const float* p) {
    return __builtin_nontemporal_load(reinterpret_cast<const vfloat4*>(p));
}

template <int CTRL>
__device__ __forceinline__ float dpp_add(float x) {
    union { float f; int i; } u, v;
    u.f = x;
    v.i = __builtin_amdgcn_update_dpp(u.i, u.i, CTRL, 0xF, 0xF, true);
    return x + v.f;
}

__device__ __forceinline__ float row_reduce16(float x) {
    x = dpp_add<0x128>(x);  // row_ror:8
    x = dpp_add<0x124>(x);  // row_ror:4
    x = dpp_add<0x122>(x);  // row_ror:2
    x = dpp_add<0x121>(x);  // row_ror:1
    return x;
}

// Project U*4 rows/wave of src through W; result*0.5 + (b or 0) -> dst4.
__device__ __forceinline__ void project_rows(
    const float* __restrict__ src, float4* __restrict__ dst4,
    const float* __restrict__ W, int n_rows, int block_i,
    float ab0, float ab1, float ab2, float ab3)
{
    const int t    = threadIdx.x;
    const int lane = t & 63;
    const int sub  = lane & 15;
    const int g    = lane >> 4;
    const int wave = t >> 6;
    const int base = block_i * (U * 16) + wave * (U * 4);
    const int last = n_rows - 1;

    int r[U], c[U];
#pragma unroll
    for (int i = 0; i < U; ++i) {
        r[i] = base + i * 4 + g;
        c[i] = r[i] > last ? last : r[i];
    }

    vfloat4 xl[U], xh[U];
#pragma unroll
    for (int i = 0; i < U; ++i) {
        xl[i] = ntload4(&src[(size_t)c[i] * D_FEAT + sub * 4]);
        xh[i] = ntload4(&src[(size_t)c[i] * D_FEAT + 64 + sub * 4]);
    }

    const float4* W4 = reinterpret_cast<const float4*>(W);
    float4 wlo[D_DOT], whi[D_DOT];
#pragma unroll
    for (int k = 0; k < D_DOT; ++k) {
        wlo[k] = W4[k * 32 + sub];
        whi[k] = W4[k * 32 + sub + 16];
    }

    float a[U][D_DOT];
#pragma unroll
    for (int i = 0; i < U; ++i)
#pragma unroll
        for (int k = 0; k < D_DOT; ++k)
            a[i][k] = dot4v(xl[i], wlo[k]) + dot4v(xh[i], whi[k]);

#pragma unroll
    for (int i = 0; i < U; ++i)
#pragma unroll
        for (int k = 0; k < D_DOT; ++k)
            a[i][k] = row_reduce16(a[i][k]);

#pragma unroll
    for (int i = 0; i < U; ++i)
        if (sub == 0 && r[i] < n_rows)
            dst4[r[i]] = make_float4(0.5f * a[i][0] + ab0, 0.5f * a[i][1] + ab1,
                                     0.5f * a[i][2] + ab2, 0.5f * a[i][3] + ab3);
}

__global__ __launch_bounds__(256, 3) void stream_proj_kernel(
    const float* __restrict__ e,
    const float* __restrict__ n,
    const float* __restrict__ W,
    const float* __restrict__ bias,
    float* __restrict__ q,    // [n_edges][4]  = 0.5*(W.e)+b
    float* __restrict__ pn,   // [n_nodes][4]  = 0.5*(W.n)
    int n_edges, int n_nodes, int eblk)
{
    if ((int)blockIdx.x < eblk) {
        const float b0 = bias[0], b1 = bias[1], b2 = bias[2], b3 = bias[3];
        project_rows(e, reinterpret_cast<float4*>(q), W, n_edges, blockIdx.x,
                     b0, b1, b2, b3);
    } else {
        project_rows(n, reinterpret_cast<float4*>(pn), W, n_nodes,
                     blockIdx.x - eblk, 0.f, 0.f, 0.f, 0.f);
    }
}

// 2 edges per lane: int2 idx loads, paired q loads, float2 store.
__global__ __launch_bounds__(256, 8) void edge_epilogue_kernel(
    const float* __restrict__ q,
    const float* __restrict__ pn,
    const int* __restrict__ src_idx,
    const int* __restrict__ dst_idx,
    float* __restrict__ out,
    int n_edges)
{
    const int tid  = blockIdx.x * 256 + threadIdx.x;
    const int base = tid * 2;
    if (base >= n_edges) return;   // n_edges even: base+1 valid when base is

    const int2 s01 = *reinterpret_cast<const int2*>(&src_idx[base]);
    const int2 d01 = *reinterpret_cast<const int2*>(&dst_idx[base]);
    const float4* q4  = reinterpret_cast<const float4*>(q);
    const float4* pn4 = reinterpret_cast<const float4*>(pn);
    const float4 q0 = q4[base], q1 = q4[base + 1];
    const float4 ps0 = pn4[s01.x], pd0 = pn4[d01.x];
    const float4 ps1 = pn4[s01.y], pd1 = pn4[d01.y];

    const float dot0 = (ps0.x + q0.x) * (pd0.x + q0.x)
                     + (ps0.y + q0.y) * (pd0.y + q0.y)
                     + (ps0.z + q0.z) * (pd0.z + q0.z)
                     + (ps0.w + q0.w) * (pd0.w + q0.w);
    const float dot1 = (ps1.x + q1.x) * (pd1.x + q1.x)
                     + (ps1.y + q1.y) * (pd1.y + q1.y)
                     + (ps1.z + q1.z) * (pd1.z + q1.z)
                     + (ps1.w + q1.w) * (pd1.w + q1.w);
    const float2 r = make_float2(1.0f / (1.0f + __expf(-dot0)),
                                 1.0f / (1.0f + __expf(-dot1)));
    *reinterpret_cast<float2*>(&out[base]) = r;
}

extern "C" void kernel_launch(void* const* d_in, const int* in_sizes, int n_in,
                              void* d_out, int out_size, void* d_ws, size_t ws_size,
                              hipStream_t stream) {
    const float* n    = (const float*)d_in[0];
    const float* e    = (const float*)d_in[1];
    const float* W    = (const float*)d_in[2];
    const float* bias = (const float*)d_in[3];
    const int*   src  = (const int*)d_in[4];
    const int*   dst  = (const int*)d_in[5];
    float* out = (float*)d_out;

    const int n_nodes = in_sizes[0] / D_FEAT;
    const int n_edges = in_sizes[1] / D_FEAT;

    // workspace layout: pn [n_nodes*4] | q [n_edges*4]
    float* pn = (float*)d_ws;
    float* q  = pn + (size_t)n_nodes * D_DOT;

    const int RPB  = U * 16;                       // 128 rows per block
    const int eblk = (n_edges + RPB - 1) / RPB;
    const int nblk = (n_nodes + RPB - 1) / RPB;
    stream_proj_kernel<<<eblk + nblk, 256, 0, stream>>>(
        e, n, W, bias, q, pn, n_edges, n_nodes, eblk);

    const int pblk = (n_edges + 511) / 512;
    edge_epilogue_kernel<<<pblk, 256, 0, stream>>>(q, pn, src, dst, out, n_edges);
}

// Round 12
// 71.047 us; speedup vs baseline: 1.0905x; 1.0905x over previous
//
#include <hip/hip_runtime.h>
#include <math.h>

#define D_FEAT 128
#define D_DOT  4
#define U      4    // row-groups per wave; 16 rows/wave, 64 rows/block (R10 sweet spot)

// Structure (validated R10): one merged pure-stream projection kernel
// (blockIdx-partitioned edges|nodes, no sync needed) + tiny gather epilogue.
// 16 lanes per row aligned to DPP rows; DPP row_ror reduce (pure VALU).
// Row streams non-temporal; q/pn stay normally cached (L2/L3 absorb).
// U=8 regressed (R11: 77.5 vs 70.8) — occupancy > per-wave batching here.

typedef float vfloat4 __attribute__((ext_vector_type(4)));

__device__ __forceinline__ float dot4v(const vfloat4 a, const float4 b) {
    return a.x * b.x + a.y * b.y + a.z * b.z + a.w * b.w;
}

__device__ __forceinline__ vfloat4 ntload4(const float* p) {
    return __builtin_nontemporal_load(reinterpret_cast<const vfloat4*>(p));
}

template <int CTRL>
__device__ __forceinline__ float dpp_add(float x) {
    union { float f; int i; } u, v;
    u.f = x;
    v.i = __builtin_amdgcn_update_dpp(u.i, u.i, CTRL, 0xF, 0xF, true);
    return x + v.f;
}

__device__ __forceinline__ float row_reduce16(float x) {
    x = dpp_add<0x128>(x);  // row_ror:8
    x = dpp_add<0x124>(x);  // row_ror:4
    x = dpp_add<0x122>(x);  // row_ror:2
    x = dpp_add<0x121>(x);  // row_ror:1
    return x;
}

// Project U*4 rows/wave of src through W; result*0.5 + (b or 0) -> dst4.
__device__ __forceinline__ void project_rows(
    const float* __restrict__ src, float4* __restrict__ dst4,
    const float* __restrict__ W, int n_rows, int block_i,
    float ab0, float ab1, float ab2, float ab3)
{
    const int t    = threadIdx.x;
    const int lane = t & 63;
    const int sub  = lane & 15;
    const int g    = lane >> 4;
    const int wave = t >> 6;
    const int base = block_i * (U * 16) + wave * (U * 4);
    const int last = n_rows - 1;

    int r[U], c[U];
#pragma unroll
    for (int i = 0; i < U; ++i) {
        r[i] = base + i * 4 + g;
        c[i] = r[i] > last ? last : r[i];
    }

    vfloat4 xl[U], xh[U];
#pragma unroll
    for (int i = 0; i < U; ++i) {
        xl[i] = ntload4(&src[(size_t)c[i] * D_FEAT + sub * 4]);
        xh[i] = ntload4(&src[(size_t)c[i] * D_FEAT + 64 + sub * 4]);
    }

    const float4* W4 = reinterpret_cast<const float4*>(W);
    float4 wlo[D_DOT], whi[D_DOT];
#pragma unroll
    for (int k = 0; k < D_DOT; ++k) {
        wlo[k] = W4[k * 32 + sub];
        whi[k] = W4[k * 32 + sub + 16];
    }

    float a[U][D_DOT];
#pragma unroll
    for (int i = 0; i < U; ++i)
#pragma unroll
        for (int k = 0; k < D_DOT; ++k)
            a[i][k] = dot4v(xl[i], wlo[k]) + dot4v(xh[i], whi[k]);

#pragma unroll
    for (int i = 0; i < U; ++i)
#pragma unroll
        for (int k = 0; k < D_DOT; ++k)
            a[i][k] = row_reduce16(a[i][k]);

#pragma unroll
    for (int i = 0; i < U; ++i)
        if (sub == 0 && r[i] < n_rows)
            dst4[r[i]] = make_float4(0.5f * a[i][0] + ab0, 0.5f * a[i][1] + ab1,
                                     0.5f * a[i][2] + ab2, 0.5f * a[i][3] + ab3);
}

__global__ __launch_bounds__(256, 4) void stream_proj_kernel(
    const float* __restrict__ e,
    const float* __restrict__ n,
    const float* __restrict__ W,
    const float* __restrict__ bias,
    float* __restrict__ q,    // [n_edges][4]  = 0.5*(W.e)+b
    float* __restrict__ pn,   // [n_nodes][4]  = 0.5*(W.n)
    int n_edges, int n_nodes, int eblk)
{
    if ((int)blockIdx.x < eblk) {
        const float b0 = bias[0], b1 = bias[1], b2 = bias[2], b3 = bias[3];
        project_rows(e, reinterpret_cast<float4*>(q), W, n_edges, blockIdx.x,
                     b0, b1, b2, b3);
    } else {
        project_rows(n, reinterpret_cast<float4*>(pn), W, n_nodes,
                     blockIdx.x - eblk, 0.f, 0.f, 0.f, 0.f);
    }
}

// 2 edges per lane: int2 idx loads, paired q loads, float2 store.
__global__ __launch_bounds__(256, 8) void edge_epilogue_kernel(
    const float* __restrict__ q,
    const float* __restrict__ pn,
    const int* __restrict__ src_idx,
    const int* __restrict__ dst_idx,
    float* __restrict__ out,
    int n_edges)
{
    const int tid  = blockIdx.x * 256 + threadIdx.x;
    const int base = tid * 2;
    if (base >= n_edges) return;   // n_edges even: base+1 valid when base is

    const int2 s01 = *reinterpret_cast<const int2*>(&src_idx[base]);
    const int2 d01 = *reinterpret_cast<const int2*>(&dst_idx[base]);
    const float4* q4  = reinterpret_cast<const float4*>(q);
    const float4* pn4 = reinterpret_cast<const float4*>(pn);
    const float4 q0 = q4[base], q1 = q4[base + 1];
    const float4 ps0 = pn4[s01.x], pd0 = pn4[d01.x];
    const float4 ps1 = pn4[s01.y], pd1 = pn4[d01.y];

    const float dot0 = (ps0.x + q0.x) * (pd0.x + q0.x)
                     + (ps0.y + q0.y) * (pd0.y + q0.y)
                     + (ps0.z + q0.z) * (pd0.z + q0.z)
                     + (ps0.w + q0.w) * (pd0.w + q0.w);
    const float dot1 = (ps1.x + q1.x) * (pd1.x + q1.x)
                     + (ps1.y + q1.y) * (pd1.y + q1.y)
                     + (ps1.z + q1.z) * (pd1.z + q1.z)
                     + (ps1.w + q1.w) * (pd1.w + q1.w);
    const float2 r = make_float2(1.0f / (1.0f + __expf(-dot0)),
                                 1.0f / (1.0f + __expf(-dot1)));
    *reinterpret_cast<float2*>(&out[base]) = r;
}

extern "C" void kernel_launch(void* const* d_in, const int* in_sizes, int n_in,
                              void* d_out, int out_size, void* d_ws, size_t ws_size,
                              hipStream_t stream) {
    const float* n    = (const float*)d_in[0];
    const float* e    = (const float*)d_in[1];
    const float* W    = (const float*)d_in[2];
    const float* bias = (const float*)d_in[3];
    const int*   src  = (const int*)d_in[4];
    const int*   dst  = (const int*)d_in[5];
    float* out = (float*)d_out;

    const int n_nodes = in_sizes[0] / D_FEAT;
    const int n_edges = in_sizes[1] / D_FEAT;

    // workspace layout: pn [n_nodes*4] | q [n_edges*4]
    float* pn = (float*)d_ws;
    float* q  = pn + (size_t)n_nodes * D_DOT;

    const int RPB  = U * 16;                       // 64 rows per block
    const int eblk = (n_edges + RPB - 1) / RPB;    // 600000/64 = 9375 exact
    const int nblk = (n_nodes + RPB - 1) / RPB;
    stream_proj_kernel<<<eblk + nblk, 256, 0, stream>>>(
        e, n, W, bias, q, pn, n_edges, n_nodes, eblk);

    const int pblk = (n_edges + 511) / 512;
    edge_epilogue_kernel<<<pblk, 256, 0, stream>>>(q, pn, src, dst, out, n_edges);
}